// Round 1
// baseline (934.118 us; speedup 1.0000x reference)
//
#include <hip/hip_runtime.h>
#include <hip/hip_cooperative_groups.h>
#include <math.h>

namespace cg = cooperative_groups;

// Problem constants (fixed by the reference).
#define NU   100000      // N users
#define MI   50000       // M items
#define NEn  150000      // NE = N + M
#define Bp   131072      // batch pairs

// Native vector types for nontemporal builtins (HIP float4 is a struct and
// __builtin_nontemporal_load rejects it).
typedef float f4v __attribute__((ext_vector_type(4)));
typedef int   i2v __attribute__((ext_vector_type(2)));

// ---------------------------------------------------------------------------
// 64-lane wave reduction (gfx950 wave = 64).
__device__ __forceinline__ float wred(float v) {
#pragma unroll
    for (int m = 32; m > 0; m >>= 1) v += __shfl_xor(v, m, 64);
    return v;
}

// ===========================================================================
// Fused persistent cooperative kernel. Phases separated by grid.sync():
//   P0: zero cnt+hdr (replaces hipMemsetAsync; ws is poisoned 0xAA each call)
//   P1: histogram of entity ids + seed out[Bp] with kl_global
//   P2: entity reparam + per-row KL (wave per row) + FUSED user/item norms
//   P3: kl_rescaled reduction + logits (wave per pair)
// All blocks co-resident: __launch_bounds__(256,8) => VGPR<=64 => 8 blk/CU.
// ===========================================================================
struct MegaArgs {
    const int*   x;
    const float* bt;
    const f4v*   et;
    const float* gbm;
    const float* gbs;
    const int*   nb;
    const float* epsb;
    const f4v*   epse;
    const float* epsg;
    int*   cnt;
    float* hdr;      // hdr[0]=user_norm hdr[1]=item_norm
    float* klpe;
    float* bia;
    f4v*   ent;      // may be null -> recompute path in P3b
    float* out;      // [0..Bp) logits, [Bp] KL scalar
};

__global__ __launch_bounds__(256, 8) void mega(MegaArgs a) {
    cg::grid_group grid = cg::this_grid();
    const int tid  = threadIdx.x;
    const int lane = tid & 63;
    const int wib  = tid >> 6;                       // wave in block (0..3)
    const int nthr = (int)gridDim.x * 256;
    const int gtid = (int)blockIdx.x * 256 + tid;
    const int nwav = nthr >> 6;
    const int gwav = (int)blockIdx.x * 4 + wib;

    __shared__ float su[4], si[4], sk[4];

    // ---- P0: zero cnt + hdr ------------------------------------------------
    for (int i = gtid; i < NEn; i += nthr) a.cnt[i] = 0;
    if (gtid < 2) a.hdr[gtid] = 0.f;
    grid.sync();

    // ---- P1: histogram; thread 0 seeds out[Bp] with kl_global --------------
    for (int t = gtid; t < 2 * Bp; t += nthr) atomicAdd(a.cnt + a.x[t], 1);
    if (gtid == 0) {
        float gm = a.gbm[0], gs = fabsf(a.gbs[0]);
        a.out[Bp] = 0.5f * (gs * gs + gm * gm - 1.0f) - __logf(gs);
    }
    grid.sync();

    // ---- P2: entity reparam + KL (one wave per row) + fused norms ----------
    // Streaming inputs read NONTEMPORAL so the ent output stays L3-resident
    // for the P3b gathers. Rows with cnt==0 skip compute (KL weight 0, never
    // gathered) but still contribute their (zero) norm term.
    float uacc = 0.f, iacc = 0.f;
    for (int e = gwav; e < NEn; e += nwav) {
        int c = a.cnt[e];
        if (lane == 0) {
            float v = (float)c / (float)a.nb[e];
            if (e < NU) uacc += v; else iacc += v;
        }
        if (c == 0) continue;                        // wave-uniform

        const f4v* row = a.et + (size_t)e * 128;
        f4v mu = __builtin_nontemporal_load(row + lane);
        f4v s4 = __builtin_nontemporal_load(row + 64 + lane);
        f4v ep = __builtin_nontemporal_load(a.epse + (size_t)e * 64 + lane);
        float scx = fabsf(s4.x), scy = fabsf(s4.y), scz = fabsf(s4.z), scw = fabsf(s4.w);

        if (a.ent) {
            f4v o;
            o.x = fmaf(scx, ep.x, mu.x);
            o.y = fmaf(scy, ep.y, mu.y);
            o.z = fmaf(scz, ep.z, mu.z);
            o.w = fmaf(scw, ep.w, mu.w);
            a.ent[(size_t)e * 64 + lane] = o;        // temporal: want L3-resident
        }

        float kl = 0.5f * (scx * scx + mu.x * mu.x - 1.0f) - __logf(scx)
                 + 0.5f * (scy * scy + mu.y * mu.y - 1.0f) - __logf(scy)
                 + 0.5f * (scz * scz + mu.z * mu.z - 1.0f) - __logf(scz)
                 + 0.5f * (scw * scw + mu.w * mu.w - 1.0f) - __logf(scw);
        kl = wred(kl);

        if (lane == 0) {
            float bmu = a.bt[2 * e];
            float bsc = fabsf(a.bt[2 * e + 1]);
            a.bia[e]  = fmaf(bsc, a.epsb[e], bmu);
            a.klpe[e] = kl + 0.5f * (bsc * bsc + bmu * bmu - 1.0f) - __logf(bsc);
        }
    }
    // norms: uacc/iacc live on lane 0 of each wave -> LDS block-reduce -> atomic
    if (lane == 0) { su[wib] = uacc; si[wib] = iacc; }
    __syncthreads();
    if (tid == 0) {
        float u = su[0] + su[1] + su[2] + su[3];
        float i = si[0] + si[1] + si[2] + si[3];
        if (u != 0.f) atomicAdd(a.hdr + 0, u);
        if (i != 0.f) atomicAdd(a.hdr + 1, i);
    }
    grid.sync();

    // ---- P3a: kl_rescaled reduction ----------------------------------------
    // scale_term: ids <= N (INCLUSIVE, reference quirk) -> N/user_norm.
    const float un  = a.hdr[0];
    const float itn = a.hdr[1];
    float kt = 0.f;
    for (int e = gtid; e < NEn; e += nthr) {
        int c = a.cnt[e];
        if (c != 0) {
            float sc = (e <= NU) ? ((float)NU / un) : ((float)MI / itn);
            kt += a.klpe[e] * ((float)c / (float)a.nb[e]) * sc;
        }
    }
    kt = wred(kt);
    if (lane == 0) sk[wib] = kt;
    __syncthreads();
    if (tid == 0) {
        float s = sk[0] + sk[1] + sk[2] + sk[3];
        if (s != 0.f) atomicAdd(a.out + Bp, s);
    }

    // ---- P3b: logits (wave per pair, grid-stride) --------------------------
    const float gb = fmaf(fabsf(a.gbs[0]), a.epsg[0], a.gbm[0]);  // hoisted once
    const bool use_ent = (a.ent != nullptr);
    for (int p = gwav; p < Bp; p += nwav) {
        i2v pr = __builtin_nontemporal_load((const i2v*)a.x + p);
        int u = pr.x, v = pr.y;
        float d;
        if (use_ent) {
            f4v ea = a.ent[(size_t)u * 64 + lane];
            f4v eb = a.ent[(size_t)v * 64 + lane];
            d = ea.x * eb.x + ea.y * eb.y + ea.z * eb.z + ea.w * eb.w;
        } else {
            const f4v* ru = a.et + (size_t)u * 128;
            const f4v* rv = a.et + (size_t)v * 128;
            f4v mu_u = ru[lane], s_u = ru[64 + lane], e_u = a.epse[(size_t)u * 64 + lane];
            f4v mu_v = rv[lane], s_v = rv[64 + lane], e_v = a.epse[(size_t)v * 64 + lane];
            float ax = fmaf(fabsf(s_u.x), e_u.x, mu_u.x), bx = fmaf(fabsf(s_v.x), e_v.x, mu_v.x);
            float ay = fmaf(fabsf(s_u.y), e_u.y, mu_u.y), by = fmaf(fabsf(s_v.y), e_v.y, mu_v.y);
            float az = fmaf(fabsf(s_u.z), e_u.z, mu_u.z), bz = fmaf(fabsf(s_v.z), e_v.z, mu_v.z);
            float aw = fmaf(fabsf(s_u.w), e_u.w, mu_u.w), bw = fmaf(fabsf(s_v.w), e_v.w, mu_v.w);
            d = ax * bx + ay * by + az * bz + aw * bw;
        }
        d = wred(d);
        if (lane == 0) {
            float r = gb + a.bia[u] + a.bia[v] + d;
            __builtin_nontemporal_store(r, a.out + p);
        }
    }
}

// ===========================================================================
// Fallback path: the previous harness-verified 6-dispatch chain, used only if
// the cooperative launch is rejected by the runtime/capture.
// ===========================================================================
__global__ __launch_bounds__(256) void k_count(const int* __restrict__ x,
                                               int* __restrict__ cnt,
                                               const float* __restrict__ gbm,
                                               const float* __restrict__ gbs,
                                               float* __restrict__ outkl) {
    int t = blockIdx.x * 256 + threadIdx.x;
    if (t < 2 * Bp) atomicAdd(cnt + x[t], 1);
    if (t == 0) {
        float gm = gbm[0];
        float gs = fabsf(gbs[0]);
        outkl[0] = 0.5f * (gs * gs + gm * gm - 1.0f) - __logf(gs);
    }
}

__global__ __launch_bounds__(256) void k_entity(
    const f4v* __restrict__ et, const f4v* __restrict__ epse,
    const float* __restrict__ bt, const float* __restrict__ epsb,
    const int* __restrict__ cnt, f4v* __restrict__ ent,
    float* __restrict__ biases, float* __restrict__ klpe)
{
    int lane = threadIdx.x & 63;
    int e    = blockIdx.x * 4 + (threadIdx.x >> 6);
    if (cnt[e] == 0) return;

    const f4v* row = et + (size_t)e * 128;
    f4v mu = __builtin_nontemporal_load(row + lane);
    f4v s4 = __builtin_nontemporal_load(row + 64 + lane);
    f4v ep = __builtin_nontemporal_load(epse + (size_t)e * 64 + lane);
    float scx = fabsf(s4.x), scy = fabsf(s4.y), scz = fabsf(s4.z), scw = fabsf(s4.w);

    if (ent) {
        f4v o;
        o.x = fmaf(scx, ep.x, mu.x);
        o.y = fmaf(scy, ep.y, mu.y);
        o.z = fmaf(scz, ep.z, mu.z);
        o.w = fmaf(scw, ep.w, mu.w);
        ent[(size_t)e * 64 + lane] = o;
    }

    float kl = 0.5f * (scx * scx + mu.x * mu.x - 1.0f) - __logf(scx)
             + 0.5f * (scy * scy + mu.y * mu.y - 1.0f) - __logf(scy)
             + 0.5f * (scz * scz + mu.z * mu.z - 1.0f) - __logf(scz)
             + 0.5f * (scw * scw + mu.w * mu.w - 1.0f) - __logf(scw);
    kl = wred(kl);

    if (lane == 0) {
        float bmu = bt[2 * e];
        float bsc = fabsf(bt[2 * e + 1]);
        biases[e] = fmaf(bsc, epsb[e], bmu);
        klpe[e]   = kl + 0.5f * (bsc * bsc + bmu * bmu - 1.0f) - __logf(bsc);
    }
}

__global__ __launch_bounds__(256) void k_norms(
    const int* __restrict__ cnt, const int* __restrict__ nb,
    float* __restrict__ hdr)
{
    int e = blockIdx.x * 256 + threadIdx.x;
    float uv = 0.f, iv = 0.f;
    if (e < NEn) {
        float v = (float)cnt[e] / (float)nb[e];
        if (e < NU) uv = v; else iv = v;
    }
    uv = wred(uv);
    iv = wred(iv);
    if ((threadIdx.x & 63) == 0) {
        if (uv != 0.f) atomicAdd(hdr + 0, uv);
        if (iv != 0.f) atomicAdd(hdr + 1, iv);
    }
}

__global__ __launch_bounds__(256) void k_logits(
    const int* __restrict__ x, const float4* __restrict__ ent,
    const float* __restrict__ biases,
    const float* __restrict__ gbm, const float* __restrict__ gbs,
    const float* __restrict__ epsg, float* __restrict__ out)
{
    int lane = threadIdx.x & 63;
    int p    = blockIdx.x * 4 + (threadIdx.x >> 6);
    int u = x[2 * p], v = x[2 * p + 1];
    float4 a = ent[(size_t)u * 64 + lane];
    float4 b = ent[(size_t)v * 64 + lane];
    float d = a.x * b.x + a.y * b.y + a.z * b.z + a.w * b.w;
    d = wred(d);
    if (lane == 0) {
        float gb = fmaf(fabsf(gbs[0]), epsg[0], gbm[0]);
        out[p] = gb + biases[u] + biases[v] + d;
    }
}

__global__ __launch_bounds__(256) void k_logits_rc(
    const int* __restrict__ x, const float4* __restrict__ et,
    const float4* __restrict__ epse, const float* __restrict__ biases,
    const float* __restrict__ gbm, const float* __restrict__ gbs,
    const float* __restrict__ epsg, float* __restrict__ out)
{
    int lane = threadIdx.x & 63;
    int p    = blockIdx.x * 4 + (threadIdx.x >> 6);
    int u = x[2 * p], v = x[2 * p + 1];
    const float4* ru = et + (size_t)u * 128;
    const float4* rv = et + (size_t)v * 128;
    float4 mu_u = ru[lane], s_u = ru[64 + lane], e_u = epse[(size_t)u * 64 + lane];
    float4 mu_v = rv[lane], s_v = rv[64 + lane], e_v = epse[(size_t)v * 64 + lane];
    float ax = fmaf(fabsf(s_u.x), e_u.x, mu_u.x), bx = fmaf(fabsf(s_v.x), e_v.x, mu_v.x);
    float ay = fmaf(fabsf(s_u.y), e_u.y, mu_u.y), by = fmaf(fabsf(s_v.y), e_v.y, mu_v.y);
    float az = fmaf(fabsf(s_u.z), e_u.z, mu_u.z), bz = fmaf(fabsf(s_v.z), e_v.z, mu_v.z);
    float aw = fmaf(fabsf(s_u.w), e_u.w, mu_u.w), bw = fmaf(fabsf(s_v.w), e_v.w, mu_v.w);
    float d = ax * bx + ay * by + az * bz + aw * bw;
    d = wred(d);
    if (lane == 0) {
        float gb = fmaf(fabsf(gbs[0]), epsg[0], gbm[0]);
        out[p] = gb + biases[u] + biases[v] + d;
    }
}

__global__ __launch_bounds__(256) void k_klred(
    const float* __restrict__ klpe, const int* __restrict__ cnt,
    const int* __restrict__ nb, const float* __restrict__ hdr,
    float* __restrict__ outkl)
{
    int e = blockIdx.x * 256 + threadIdx.x;
    float t = 0.f;
    if (e < NEn) {
        int c = cnt[e];
        if (c != 0) {
            float sc = (e <= NU) ? ((float)NU / hdr[0]) : ((float)MI / hdr[1]);
            t = klpe[e] * ((float)c / (float)nb[e]) * sc;
        }
    }
    t = wred(t);
    if ((threadIdx.x & 63) == 0 && t != 0.f) atomicAdd(outkl, t);
}

// ---------------------------------------------------------------------------
extern "C" void kernel_launch(void* const* d_in, const int* in_sizes, int n_in,
                              void* d_out, int out_size, void* d_ws, size_t ws_size,
                              hipStream_t stream)
{
    const int*   x    = (const int*)d_in[0];
    const float* bt   = (const float*)d_in[1];
    const float* et   = (const float*)d_in[2];
    const float* gbm  = (const float*)d_in[3];
    const float* gbs  = (const float*)d_in[4];
    const int*   nb   = (const int*)d_in[5];
    const float* epsb = (const float*)d_in[6];
    const float* epse = (const float*)d_in[7];
    const float* epsg = (const float*)d_in[8];
    float* out = (float*)d_out;   // [0..B) logits, [B] KL scalar

    char*  ws   = (char*)d_ws;
    float* hdr  = (float*)ws;                              // hdr[0]=user hdr[1]=item
    int*   cnt  = (int*)  (ws + 64);                       // NE ints
    float* klpe = (float*)(ws + 64 + (size_t)NEn * 4);     // NE floats
    float* bia  = (float*)(ws + 64 + (size_t)NEn * 8);     // NE floats
    size_t entoff = 64 + (size_t)NEn * 12;
    f4v* ent = nullptr;
    if (ws_size >= entoff + (size_t)NEn * 1024)            // ~155.4 MB total
        ent = (f4v*)(ws + entoff);

    MegaArgs a;
    a.x = x; a.bt = bt; a.et = (const f4v*)et; a.gbm = gbm; a.gbs = gbs;
    a.nb = nb; a.epsb = epsb; a.epse = (const f4v*)epse; a.epsg = epsg;
    a.cnt = cnt; a.hdr = hdr; a.klpe = klpe; a.bia = bia; a.ent = ent; a.out = out;

    // Size the cooperative grid so all blocks are co-resident.
    int bpc = 0;
    if (hipOccupancyMaxActiveBlocksPerMultiprocessor(&bpc, mega, 256, 0) != hipSuccess)
        bpc = 0;
    if (bpc > 8) bpc = 8;                                  // 2048 thr/CU cap

    if (bpc > 0) {
        int grid = bpc * 256;                              // 256 CUs on MI355X
        void* params[] = { (void*)&a };
        if (hipLaunchCooperativeKernel(mega, dim3(grid), dim3(256),
                                       params, 0u, stream) == hipSuccess)
            return;
    }

    // ---------- fallback: previous verified 6-dispatch path ----------
    (void)hipMemsetAsync(ws, 0, 64 + (size_t)NEn * 4, stream);
    k_count <<<(2 * Bp + 255) / 256, 256, 0, stream>>>(x, cnt, gbm, gbs, out + Bp);
    k_entity<<<NEn / 4,              256, 0, stream>>>((const f4v*)et, (const f4v*)epse,
                                                       bt, epsb, cnt, ent, bia, klpe);
    k_norms <<<(NEn + 255) / 256,    256, 0, stream>>>(cnt, nb, hdr);
    if (ent)
        k_logits   <<<Bp / 4, 256, 0, stream>>>(x, (const float4*)ent, bia, gbm, gbs, epsg, out);
    else
        k_logits_rc<<<Bp / 4, 256, 0, stream>>>(x, (const float4*)et,
                                                (const float4*)epse, bia,
                                                gbm, gbs, epsg, out);
    k_klred <<<(NEn + 255) / 256,    256, 0, stream>>>(klpe, cnt, nb, hdr, out + Bp);
}

// Round 2
// 572.654 us; speedup vs baseline: 1.6312x; 1.6312x over previous
//
#include <hip/hip_runtime.h>
#include <math.h>

// Problem constants (fixed by the reference).
#define NU   100000      // N users
#define MI   50000       // M items
#define NEn  150000      // NE = N + M
#define Bp   131072      // batch pairs

// Native vector types (__builtin_nontemporal_* rejects struct float4).
typedef float    f4v __attribute__((ext_vector_type(4)));
typedef _Float16 h8v __attribute__((ext_vector_type(8)));   // 16 B of fp16
typedef _Float16 h4v __attribute__((ext_vector_type(4)));   // 8 B of fp16

// ---------------------------------------------------------------------------
// 64-lane wave reduction (gfx950 wave = 64).
__device__ __forceinline__ float wred(float v) {
#pragma unroll
    for (int m = 32; m > 0; m >>= 1) v += __shfl_xor(v, m, 64);
    return v;
}
// 32-lane (half-wave) reduction: xor masks 16..1 stay within each half.
__device__ __forceinline__ float hred(float v) {
#pragma unroll
    for (int m = 16; m > 0; m >>= 1) v += __shfl_xor(v, m, 64);
    return v;
}

// ---------------------------------------------------------------------------
// K1: histogram of entity ids (cnt zeroed by memsetAsync beforehand).
// Thread 0 also seeds out[Bp] with kl_global (klred atomically adds onto it).
__global__ __launch_bounds__(256) void k_count(const int* __restrict__ x,
                                               int* __restrict__ cnt,
                                               const float* __restrict__ gbm,
                                               const float* __restrict__ gbs,
                                               float* __restrict__ outkl) {
    int t = blockIdx.x * 256 + threadIdx.x;
    if (t < 2 * Bp) atomicAdd(cnt + x[t], 1);
    if (t == 0) {
        float gm = gbm[0];
        float gs = fabsf(gbs[0]);
        outkl[0] = 0.5f * (gs * gs + gm * gm - 1.0f) - __logf(gs);
    }
}

// ---------------------------------------------------------------------------
// K2: entity reparam + KL (wave per row) with FUSED user/item norms.
//   blocks [0, NEn/4)            : entity work, one wave per row
//   blocks [NEn/4, NEn/4 + 586)  : norms (cnt/nb sums), independent of entity
// Streaming inputs (et, epse) read NONTEMPORAL so the fp16 ent output stays
// cache-resident for K3's gathers. Rows with cnt==0 skipped (KL weight 0,
// never gathered).
__global__ __launch_bounds__(256) void k_entnorm(
    const f4v* __restrict__ et,       // entity_table, NE x 2D (row = 128 f4v)
    const f4v* __restrict__ epse,     // eps_entity,   NE x D  (row = 64 f4v)
    const float* __restrict__ bt,     // bias_table,   NE x 2
    const float* __restrict__ epsb,   // eps_bias,     NE
    const int*   __restrict__ cnt,
    const int*   __restrict__ nb,
    h4v*   __restrict__ enth,         // out: entities_all fp16 (row = 64 h4v = 512 B); may be null
    float* __restrict__ biases,       // out: biases_all
    float* __restrict__ klpe,         // out: kl_bias + kl_entity per row
    float* __restrict__ hdr)          // out: hdr[0]=user_norm hdr[1]=item_norm
{
    if (blockIdx.x >= NEn / 4) {
        // ---- norms part ----
        int e = (blockIdx.x - NEn / 4) * 256 + threadIdx.x;
        float uv = 0.f, iv = 0.f;
        if (e < NEn) {
            float v = (float)cnt[e] / (float)nb[e];
            if (e < NU) uv = v; else iv = v;
        }
        uv = wred(uv);
        iv = wred(iv);
        if ((threadIdx.x & 63) == 0) {
            if (uv != 0.f) atomicAdd(hdr + 0, uv);
            if (iv != 0.f) atomicAdd(hdr + 1, iv);
        }
        return;
    }

    // ---- entity part ----
    int lane = threadIdx.x & 63;
    int e    = blockIdx.x * 4 + (threadIdx.x >> 6);
    if (cnt[e] == 0) return;  // wave-uniform

    const f4v* row = et + (size_t)e * 128;
    f4v mu = __builtin_nontemporal_load(row + lane);
    f4v s4 = __builtin_nontemporal_load(row + 64 + lane);
    f4v ep = __builtin_nontemporal_load(epse + (size_t)e * 64 + lane);
    float scx = fabsf(s4.x), scy = fabsf(s4.y), scz = fabsf(s4.z), scw = fabsf(s4.w);

    if (enth) {
        float ox = fmaf(scx, ep.x, mu.x);
        float oy = fmaf(scy, ep.y, mu.y);
        float oz = fmaf(scz, ep.z, mu.z);
        float ow = fmaf(scw, ep.w, mu.w);
        h4v oh;
        oh.x = (_Float16)ox; oh.y = (_Float16)oy;
        oh.z = (_Float16)oz; oh.w = (_Float16)ow;
        enth[(size_t)e * 64 + lane] = oh;   // temporal: want this cache-resident
    }

    float kl = 0.5f * (scx * scx + mu.x * mu.x - 1.0f) - __logf(scx)
             + 0.5f * (scy * scy + mu.y * mu.y - 1.0f) - __logf(scy)
             + 0.5f * (scz * scz + mu.z * mu.z - 1.0f) - __logf(scz)
             + 0.5f * (scw * scw + mu.w * mu.w - 1.0f) - __logf(scw);
    kl = wred(kl);

    if (lane == 0) {
        float bmu = bt[2 * e];
        float bsc = fabsf(bt[2 * e + 1]);
        biases[e] = fmaf(bsc, epsb[e], bmu);
        klpe[e]   = kl + 0.5f * (bsc * bsc + bmu * bmu - 1.0f) - __logf(bsc);
    }
}

// ---------------------------------------------------------------------------
// K3: logits (fp16 ent, TWO pairs per wave: 32 lanes x 16 B per row) with
// FUSED kl_rescaled reduction.
//   blocks [0, Bp/8)          : logits, 8 pairs per 256-thread block
//   blocks [Bp/8, Bp/8 + 586) : klred -> atomic onto out[Bp]
__global__ __launch_bounds__(256) void k_logred(
    const int* __restrict__ x,
    const h8v* __restrict__ enth,     // row = 32 h8v (512 B)
    const float* __restrict__ biases,
    const float* __restrict__ gbm, const float* __restrict__ gbs,
    const float* __restrict__ epsg,
    const float* __restrict__ klpe, const int* __restrict__ cnt,
    const int* __restrict__ nb, const float* __restrict__ hdr,
    float* __restrict__ out)
{
    if (blockIdx.x >= Bp / 8) {
        // ---- klred part ----
        // scale_term: ids <= N (INCLUSIVE, reference quirk) -> N/user_norm.
        int e = (blockIdx.x - Bp / 8) * 256 + threadIdx.x;
        float t = 0.f;
        if (e < NEn) {
            int c = cnt[e];
            if (c != 0) {
                float sc = (e <= NU) ? ((float)NU / hdr[0]) : ((float)MI / hdr[1]);
                t = klpe[e] * ((float)c / (float)nb[e]) * sc;
            }
        }
        t = wred(t);
        if ((threadIdx.x & 63) == 0 && t != 0.f) atomicAdd(out + Bp, t);
        return;
    }

    // ---- logits part ----
    int lane = threadIdx.x & 63;
    int sub  = lane & 31;                      // lane within half-wave
    int p    = blockIdx.x * 8 + ((threadIdx.x >> 6) << 1) + (lane >> 5);
    int u = x[2 * p], v = x[2 * p + 1];
    float bu = biases[u];                      // prefetch: overlaps the gathers
    float bv = biases[v];
    h8v a = enth[(size_t)u * 32 + sub];
    h8v b = enth[(size_t)v * 32 + sub];
    float d = 0.f;
#pragma unroll
    for (int i = 0; i < 8; ++i) d = fmaf((float)a[i], (float)b[i], d);
    d = hred(d);
    if (sub == 0) {
        float gb = fmaf(fabsf(gbs[0]), epsg[0], gbm[0]);
        out[p] = gb + bu + bv + d;
    }
}

// ---------------------------------------------------------------------------
// Fallback (ws too small for fp16 ent): recompute rows in the gather.
__global__ __launch_bounds__(256) void k_logits_rc(
    const int* __restrict__ x, const float4* __restrict__ et,
    const float4* __restrict__ epse, const float* __restrict__ biases,
    const float* __restrict__ gbm, const float* __restrict__ gbs,
    const float* __restrict__ epsg, float* __restrict__ out)
{
    int lane = threadIdx.x & 63;
    int p    = blockIdx.x * 4 + (threadIdx.x >> 6);
    int u = x[2 * p], v = x[2 * p + 1];
    const float4* ru = et + (size_t)u * 128;
    const float4* rv = et + (size_t)v * 128;
    float4 mu_u = ru[lane], s_u = ru[64 + lane], e_u = epse[(size_t)u * 64 + lane];
    float4 mu_v = rv[lane], s_v = rv[64 + lane], e_v = epse[(size_t)v * 64 + lane];
    float ax = fmaf(fabsf(s_u.x), e_u.x, mu_u.x), bx = fmaf(fabsf(s_v.x), e_v.x, mu_v.x);
    float ay = fmaf(fabsf(s_u.y), e_u.y, mu_u.y), by = fmaf(fabsf(s_v.y), e_v.y, mu_v.y);
    float az = fmaf(fabsf(s_u.z), e_u.z, mu_u.z), bz = fmaf(fabsf(s_v.z), e_v.z, mu_v.z);
    float aw = fmaf(fabsf(s_u.w), e_u.w, mu_u.w), bw = fmaf(fabsf(s_v.w), e_v.w, mu_v.w);
    float d = ax * bx + ay * by + az * bz + aw * bw;
    d = wred(d);
    if (lane == 0) {
        float gb = fmaf(fabsf(gbs[0]), epsg[0], gbm[0]);
        out[p] = gb + biases[u] + biases[v] + d;
    }
}

__global__ __launch_bounds__(256) void k_klred(
    const float* __restrict__ klpe, const int* __restrict__ cnt,
    const int* __restrict__ nb, const float* __restrict__ hdr,
    float* __restrict__ outkl)
{
    int e = blockIdx.x * 256 + threadIdx.x;
    float t = 0.f;
    if (e < NEn) {
        int c = cnt[e];
        if (c != 0) {
            float sc = (e <= NU) ? ((float)NU / hdr[0]) : ((float)MI / hdr[1]);
            t = klpe[e] * ((float)c / (float)nb[e]) * sc;
        }
    }
    t = wred(t);
    if ((threadIdx.x & 63) == 0 && t != 0.f) atomicAdd(outkl, t);
}

// ---------------------------------------------------------------------------
extern "C" void kernel_launch(void* const* d_in, const int* in_sizes, int n_in,
                              void* d_out, int out_size, void* d_ws, size_t ws_size,
                              hipStream_t stream)
{
    const int*   x    = (const int*)d_in[0];
    const float* bt   = (const float*)d_in[1];
    const float* et   = (const float*)d_in[2];
    const float* gbm  = (const float*)d_in[3];
    const float* gbs  = (const float*)d_in[4];
    const int*   nb   = (const int*)d_in[5];
    const float* epsb = (const float*)d_in[6];
    const float* epse = (const float*)d_in[7];
    const float* epsg = (const float*)d_in[8];
    float* out = (float*)d_out;   // [0..Bp) logits, [Bp] KL scalar

    char*  ws   = (char*)d_ws;
    float* hdr  = (float*)ws;                              // hdr[0]=user hdr[1]=item
    int*   cnt  = (int*)  (ws + 64);                       // NE ints
    float* klpe = (float*)(ws + 64 + (size_t)NEn * 4);     // NE floats
    float* bia  = (float*)(ws + 64 + (size_t)NEn * 8);     // NE floats
    size_t entoff = 64 + (size_t)NEn * 12;
    h4v* enth = nullptr;
    if (ws_size >= entoff + (size_t)NEn * 512)             // fp16 rows: 512 B each
        enth = (h4v*)(ws + entoff);

    const int NORMB = (NEn + 255) / 256;                   // 586

    // ws is re-poisoned to 0xAA before every timed call: zero hdr + cnt each time.
    (void)hipMemsetAsync(ws, 0, 64 + (size_t)NEn * 4, stream);

    k_count<<<(2 * Bp + 255) / 256, 256, 0, stream>>>(x, cnt, gbm, gbs, out + Bp);

    k_entnorm<<<NEn / 4 + NORMB, 256, 0, stream>>>(
        (const f4v*)et, (const f4v*)epse, bt, epsb, cnt, nb,
        enth, bia, klpe, hdr);

    if (enth) {
        k_logred<<<Bp / 8 + NORMB, 256, 0, stream>>>(
            x, (const h8v*)enth, bia, gbm, gbs, epsg,
            klpe, cnt, nb, hdr, out);
    } else {
        k_logits_rc<<<Bp / 4, 256, 0, stream>>>(x, (const float4*)et,
                                                (const float4*)epse, bia,
                                                gbm, gbs, epsg, out);
        k_klred<<<NORMB, 256, 0, stream>>>(klpe, cnt, nb, hdr, out + Bp);
    }
}

// Round 4
// 529.458 us; speedup vs baseline: 1.7643x; 1.0816x over previous
//
#include <hip/hip_runtime.h>
#include <math.h>

// Problem constants (fixed by the reference).
#define NU   100000      // N users
#define MI   50000       // M items
#define NEn  150000      // NE = N + M
#define Bp   131072      // batch pairs

// Grid partitioning.
#define CB   256                     // count blocks in K1 (2*Bp/4/256)
#define EB   (NEn / 4)               // entity blocks in K1 (wave per row)
#define TB   ((NEn + 255) / 256)     // tail (klred-partial) blocks in K2 = 586
#define LB   (Bp / 8)                // logits blocks in K2

// Native vector types (__builtin_nontemporal_* rejects struct float4).
typedef float    f4v __attribute__((ext_vector_type(4)));
typedef _Float16 h8v __attribute__((ext_vector_type(8)));   // 16 B of fp16
typedef _Float16 h4v __attribute__((ext_vector_type(4)));   // 8 B of fp16

// ---------------------------------------------------------------------------
// 64-lane wave reduction (gfx950 wave = 64).
__device__ __forceinline__ float wred(float v) {
#pragma unroll
    for (int m = 32; m > 0; m >>= 1) v += __shfl_xor(v, m, 64);
    return v;
}
// 32-lane (half-wave) reduction: xor masks 16..1 stay within each half.
__device__ __forceinline__ float hred(float v) {
#pragma unroll
    for (int m = 16; m > 0; m >>= 1) v += __shfl_xor(v, m, 64);
    return v;
}

// ---------------------------------------------------------------------------
// K1: histogram (blocks [0,CB)) CONCURRENT with entity reparam+KL
// (blocks [CB, CB+EB), one wave per row, ALL rows — no cnt dependency).
// cnt zeroed by the preceding hipMemsetAsync. Entity streams are nontemporal
// so the fp16 enth output stays cache-resident for K2's gathers.
__global__ __launch_bounds__(256) void k_cnt_ent(
    const int4* __restrict__ x4,      // x as int4 (2*Bp/4 elements)
    const f4v* __restrict__ et,       // entity_table, NE x 2D (row = 128 f4v)
    const f4v* __restrict__ epse,     // eps_entity,   NE x D  (row = 64 f4v)
    const float* __restrict__ bt,     // bias_table,   NE x 2
    const float* __restrict__ epsb,   // eps_bias,     NE
    const float* __restrict__ gbm,
    const float* __restrict__ gbs,
    int*   __restrict__ cnt,
    h4v*   __restrict__ enth,         // out: entities_all fp16 (512 B rows); may be null
    float* __restrict__ bia,          // out: biases_all
    float* __restrict__ klpe,         // out: kl_bias + kl_entity per row
    float* __restrict__ outkl)        // out[Bp] seeded with kl_global
{
    if (blockIdx.x < CB) {
        // ---- count part: 4 ids per thread ----
        int t = blockIdx.x * 256 + threadIdx.x;
        int4 v = x4[t];
        atomicAdd(cnt + v.x, 1);
        atomicAdd(cnt + v.y, 1);
        atomicAdd(cnt + v.z, 1);
        atomicAdd(cnt + v.w, 1);
        if (t == 0) {
            float gm = gbm[0];
            float gs = fabsf(gbs[0]);
            outkl[0] = 0.5f * (gs * gs + gm * gm - 1.0f) - __logf(gs);
        }
        return;
    }

    // ---- entity part: one wave per row, all NEn rows ----
    int lane = threadIdx.x & 63;
    int e    = (blockIdx.x - CB) * 4 + (threadIdx.x >> 6);

    const f4v* row = et + (size_t)e * 128;
    f4v mu = __builtin_nontemporal_load(row + lane);
    f4v s4 = __builtin_nontemporal_load(row + 64 + lane);
    f4v ep = __builtin_nontemporal_load(epse + (size_t)e * 64 + lane);
    float scx = fabsf(s4.x), scy = fabsf(s4.y), scz = fabsf(s4.z), scw = fabsf(s4.w);

    if (enth) {
        h4v oh;
        oh.x = (_Float16)fmaf(scx, ep.x, mu.x);
        oh.y = (_Float16)fmaf(scy, ep.y, mu.y);
        oh.z = (_Float16)fmaf(scz, ep.z, mu.z);
        oh.w = (_Float16)fmaf(scw, ep.w, mu.w);
        enth[(size_t)e * 64 + lane] = oh;   // temporal: want this cache-resident
    }

    float kl = 0.5f * (scx * scx + mu.x * mu.x - 1.0f) - __logf(scx)
             + 0.5f * (scy * scy + mu.y * mu.y - 1.0f) - __logf(scy)
             + 0.5f * (scz * scz + mu.z * mu.z - 1.0f) - __logf(scz)
             + 0.5f * (scw * scw + mu.w * mu.w - 1.0f) - __logf(scw);
    kl = wred(kl);

    if (lane == 0) {
        float bmu = bt[2 * e];
        float bsc = fabsf(bt[2 * e + 1]);
        bia[e]  = fmaf(bsc, epsb[e], bmu);
        klpe[e] = kl + 0.5f * (bsc * bsc + bmu * bmu - 1.0f) - __logf(bsc);
    }
}

// ---------------------------------------------------------------------------
// K2: klred partial sums (blocks [0,TB)) CONCURRENT with logits
// (blocks [TB, TB+LB), fp16 gather, 2 pairs per wave / 16 B per lane).
// Partial-sum refactor: kl_rescaled = NU*A/U + MI*B/I with
//   U = sum_{e<NU}  c/nb          I = sum_{e>=NU} c/nb
//   A = sum_{e<=NU} klpe*c/nb     B = sum_{e>NU}  klpe*c/nb   (<=N quirk)
// hdr[0..3] = U, I, A, B (zeroed by memset); finalized by K3.
__global__ __launch_bounds__(256) void k_log_tail(
    const int* __restrict__ x,
    const h8v* __restrict__ enth,     // row = 32 h8v (512 B); may be null
    const float* __restrict__ bia,
    const float* __restrict__ gbm, const float* __restrict__ gbs,
    const float* __restrict__ epsg,
    const int* __restrict__ cnt, const int* __restrict__ nb,
    const float* __restrict__ klpe,
    float* __restrict__ hdr,
    float* __restrict__ out)
{
    if (blockIdx.x < TB) {
        // ---- klred/norms partial part ----
        int e = blockIdx.x * 256 + threadIdx.x;
        float u = 0.f, i = 0.f, aa = 0.f, bb = 0.f;
        if (e < NEn) {
            float v  = (float)cnt[e] / (float)nb[e];
            float kv = klpe[e] * v;          // klpe valid for ALL rows now
            if (e < NU)  u  = v;  else i  = v;
            if (e <= NU) aa = kv; else bb = kv;
        }
        u = wred(u); i = wred(i); aa = wred(aa); bb = wred(bb);
        __shared__ float s[4][4];
        int wib = threadIdx.x >> 6;
        if ((threadIdx.x & 63) == 0) {
            s[wib][0] = u; s[wib][1] = i; s[wib][2] = aa; s[wib][3] = bb;
        }
        __syncthreads();
        if (threadIdx.x < 4) {
            float t = s[0][threadIdx.x] + s[1][threadIdx.x]
                    + s[2][threadIdx.x] + s[3][threadIdx.x];
            if (t != 0.f) atomicAdd(hdr + threadIdx.x, t);
        }
        return;
    }

    // ---- logits part (verified R2 structure) ----
    int lane = threadIdx.x & 63;
    int sub  = lane & 31;                      // lane within half-wave
    int p    = (blockIdx.x - TB) * 8 + ((threadIdx.x >> 6) << 1) + (lane >> 5);
    int u = x[2 * p], v = x[2 * p + 1];
    float bu = bia[u];                         // prefetch: overlaps the gathers
    float bv = bia[v];
    h8v a = enth[(size_t)u * 32 + sub];
    h8v b = enth[(size_t)v * 32 + sub];
    float d = 0.f;
#pragma unroll
    for (int i = 0; i < 8; ++i) d = fmaf((float)a[i], (float)b[i], d);
    d = hred(d);
    if (sub == 0) {
        float gb = fmaf(fabsf(gbs[0]), epsg[0], gbm[0]);
        __builtin_nontemporal_store(gb + bu + bv + d, out + p);
    }
}

// ---------------------------------------------------------------------------
// K3: finalize KL scalar. out[Bp] already holds kl_global (K1).
__global__ void k_fin(const float* __restrict__ hdr, float* __restrict__ outkl) {
    if (threadIdx.x == 0)
        outkl[0] += (float)NU * hdr[2] / hdr[0] + (float)MI * hdr[3] / hdr[1];
}

// ---------------------------------------------------------------------------
// Fallback gather (ws too small for fp16 ent): recompute rows. Never expected
// to run (ws ~1.2 GB); kept for safety.
__global__ __launch_bounds__(256) void k_logits_rc(
    const int* __restrict__ x, const float4* __restrict__ et,
    const float4* __restrict__ epse, const float* __restrict__ bia,
    const float* __restrict__ gbm, const float* __restrict__ gbs,
    const float* __restrict__ epsg, float* __restrict__ out)
{
    int lane = threadIdx.x & 63;
    int p    = blockIdx.x * 4 + (threadIdx.x >> 6);
    int u = x[2 * p], v = x[2 * p + 1];
    const float4* ru = et + (size_t)u * 128;
    const float4* rv = et + (size_t)v * 128;
    float4 mu_u = ru[lane], s_u = ru[64 + lane], e_u = epse[(size_t)u * 64 + lane];
    float4 mu_v = rv[lane], s_v = rv[64 + lane], e_v = epse[(size_t)v * 64 + lane];
    float ax = fmaf(fabsf(s_u.x), e_u.x, mu_u.x), bx = fmaf(fabsf(s_v.x), e_v.x, mu_v.x);
    float ay = fmaf(fabsf(s_u.y), e_u.y, mu_u.y), by = fmaf(fabsf(s_v.y), e_v.y, mu_v.y);
    float az = fmaf(fabsf(s_u.z), e_u.z, mu_u.z), bz = fmaf(fabsf(s_v.z), e_v.z, mu_v.z);
    float aw = fmaf(fabsf(s_u.w), e_u.w, mu_u.w), bw = fmaf(fabsf(s_v.w), e_v.w, mu_v.w);
    float d = ax * bx + ay * by + az * bz + aw * bw;
    d = wred(d);
    if (lane == 0) {
        float gb = fmaf(fabsf(gbs[0]), epsg[0], gbm[0]);
        out[p] = gb + bia[u] + bia[v] + d;
    }
}

// ---------------------------------------------------------------------------
extern "C" void kernel_launch(void* const* d_in, const int* in_sizes, int n_in,
                              void* d_out, int out_size, void* d_ws, size_t ws_size,
                              hipStream_t stream)
{
    const int*   x    = (const int*)d_in[0];
    const float* bt   = (const float*)d_in[1];
    const float* et   = (const float*)d_in[2];
    const float* gbm  = (const float*)d_in[3];
    const float* gbs  = (const float*)d_in[4];
    const int*   nb   = (const int*)d_in[5];
    const float* epsb = (const float*)d_in[6];
    const float* epse = (const float*)d_in[7];
    const float* epsg = (const float*)d_in[8];
    float* out = (float*)d_out;   // [0..Bp) logits, [Bp] KL scalar

    char*  ws   = (char*)d_ws;
    float* hdr  = (float*)ws;                              // hdr[0..3] = U,I,A,B
    int*   cnt  = (int*)  (ws + 64);                       // NE ints
    float* klpe = (float*)(ws + 64 + (size_t)NEn * 4);     // NE floats
    float* bia  = (float*)(ws + 64 + (size_t)NEn * 8);     // NE floats
    size_t entoff = 64 + (size_t)NEn * 12;                 // 16B-aligned
    h4v* enth = nullptr;
    if (ws_size >= entoff + (size_t)NEn * 512)             // fp16 rows: 512 B each
        enth = (h4v*)(ws + entoff);

    // ws is re-poisoned to 0xAA before every timed call: zero hdr + cnt.
    (void)hipMemsetAsync(ws, 0, 64 + (size_t)NEn * 4, stream);

    // K1: count (256 blocks) || entity reparam+KL (NEn/4 blocks).
    k_cnt_ent<<<CB + EB, 256, 0, stream>>>(
        (const int4*)x, (const f4v*)et, (const f4v*)epse, bt, epsb,
        gbm, gbs, cnt, enth, bia, klpe, out + Bp);

    // K2: klred partials (TB blocks) || logits (LB blocks).
    if (enth) {
        k_log_tail<<<TB + LB, 256, 0, stream>>>(
            x, (const h8v*)enth, bia, gbm, gbs, epsg,
            cnt, nb, klpe, hdr, out);
    } else {
        k_log_tail<<<TB, 256, 0, stream>>>(     // tail-only
            x, nullptr, bia, gbm, gbs, epsg, cnt, nb, klpe, hdr, out);
        k_logits_rc<<<Bp / 4, 256, 0, stream>>>(x, (const float4*)et,
                                                (const float4*)epse, bia,
                                                gbm, gbs, epsg, out);
    }

    // K3: finalize KL scalar.
    k_fin<<<1, 64, 0, stream>>>(hdr, out + Bp);
}